// Round 7
// baseline (333.349 us; speedup 1.0000x reference)
//
#include <hip/hip_runtime.h>
#include <hip/hip_bf16.h>
#include <math.h>

// Problem constants
#define BB 4
#define CC 256
#define NN 4096          // H*W
#define EE 96
#define NTOT (BB*NN)     // 16384 rows

typedef __attribute__((ext_vector_type(8))) short bf16x8;
typedef __attribute__((ext_vector_type(4))) short bf16x4;
typedef __attribute__((ext_vector_type(4))) float f32x4;

__device__ __forceinline__ short f2bf(float x) {
    __hip_bfloat16 h = __float2bfloat16(x);
    return *reinterpret_cast<short*>(&h);
}
__device__ __forceinline__ float bf2f(short s) {
    unsigned int u = ((unsigned int)(unsigned short)s) << 16;
    float f;
    __builtin_memcpy(&f, &u, 4);
    return f;
}
__device__ __forceinline__ float gelu_exact(float v) {
    return 0.5f * v * (1.0f + erff(v * 0.70710678118654752f));
}
// async global->LDS, 16B per lane; LDS dest = uniform base + lane*16
__device__ __forceinline__ void gld16(void* lds, const void* g) {
    __builtin_amdgcn_global_load_lds(
        (const __attribute__((address_space(1))) unsigned int*)g,
        (__attribute__((address_space(3))) unsigned int*)lds, 16, 0, 0);
}

// Weight arena offsets (shorts). wg split into 256-stride matrix + last col.
#define OFF_WQ  0
#define OFF_WK  24576
#define OFF_WV  49152
#define OFF_WO  114688
#define OFF_WD1 180224
#define OFF_WD2 311296
#define OFF_WG  376832
#define OFF_WGL 442368
#define W16_TOTAL 442624

// ---------------------------------------------------------------------------
// Kernel 1: fused weight-convert + channel LayerNorm (16-position tiles).
// Grid 1024 (4 blocks/CU). Emits bf16 Xt16 (=x) and Xn16 (normed), row-major.
// ---------------------------------------------------------------------------
__global__ __launch_bounds__(256) void ln_kernel(
    const float* __restrict__ x, const float* __restrict__ gamma,
    const float* __restrict__ beta,
    const float* __restrict__ wq, const float* __restrict__ wk,
    const float* __restrict__ wv, const float* __restrict__ wo,
    const float* __restrict__ wd1, const float* __restrict__ wd2,
    const float* __restrict__ wg, short* __restrict__ W16,
    short* __restrict__ Xt16, short* __restrict__ Xn16)
{
    __shared__ float tile[256 * 17];
    __shared__ float psum[16][16], psq[16][16];
    __shared__ float mu_s[16], rs_s[16];
    __shared__ float gs[256], bs[256];
    const int tid = threadIdx.x;
    const int b  = blockIdx.x >> 8;
    const int p0 = (blockIdx.x & 255) * 16;

    // fused weight conversion (2 elements per thread across the grid)
    {
        int i0 = blockIdx.x * 256 + tid;
        #pragma unroll
        for (int j = 0; j < 2; ++j) {
            int i = i0 + j * 262144;
            if (i < W16_TOTAL) {
                float v;
                if      (i < OFF_WK)  v = wq[i];
                else if (i < OFF_WV)  v = wk[i - OFF_WK];
                else if (i < OFF_WO)  v = wv[i - OFF_WV];
                else if (i < OFF_WD1) v = wo[i - OFF_WO];
                else if (i < OFF_WD2) v = wd1[i - OFF_WD1];
                else if (i < OFF_WG)  v = wd2[i - OFF_WD2];
                else if (i < OFF_WGL) { int l = i - OFF_WG; v = wg[(l >> 8) * 257 + (l & 255)]; }
                else                  v = wg[(i - OFF_WGL) * 257 + 256];
                W16[i] = f2bf(v);
            }
        }
    }

    const float* xb = x + (size_t)b * CC * NN;
    gs[tid] = gamma[tid];
    bs[tid] = beta[tid];
    #pragma unroll
    for (int i = 0; i < 4; ++i) {
        int idx = tid + i * 256;
        int c = idx >> 2, p4 = (idx & 3) * 4;
        float4 v = *(const float4*)&xb[(size_t)c * NN + p0 + p4];
        tile[c * 17 + p4]     = v.x;
        tile[c * 17 + p4 + 1] = v.y;
        tile[c * 17 + p4 + 2] = v.z;
        tile[c * 17 + p4 + 3] = v.w;
    }
    __syncthreads();
    {
        int col = tid & 15, part = tid >> 4;
        float s = 0.f, sq = 0.f;
        for (int r = part * 16; r < part * 16 + 16; ++r) {
            float v = tile[r * 17 + col];
            s += v; sq += v * v;
        }
        psum[part][col] = s; psq[part][col] = sq;
    }
    __syncthreads();
    if (tid < 16) {
        float S = 0.f, SQ = 0.f;
        #pragma unroll
        for (int j = 0; j < 16; ++j) { S += psum[j][tid]; SQ += psq[j][tid]; }
        float mu = S / 256.0f;
        float var = SQ / 256.0f - mu * mu;
        mu_s[tid] = mu;
        rs_s[tid] = rsqrtf(var + 1e-5f);
    }
    __syncthreads();
    {
        int p = tid >> 4, c16 = (tid & 15) * 16;
        float mu = mu_s[p], rcp = rs_s[p];
        size_t o = ((size_t)b * NN + p0 + p) * CC + c16;
        bf16x8 xt0, xn0, xt1, xn1;
        #pragma unroll
        for (int j = 0; j < 8; ++j) {
            float v = tile[(c16 + j) * 17 + p];
            float n = (v - mu) * rcp * gs[c16 + j] + bs[c16 + j];
            xt0[j] = f2bf(v); xn0[j] = f2bf(n);
            float v2 = tile[(c16 + 8 + j) * 17 + p];
            float n2 = (v2 - mu) * rcp * gs[c16 + 8 + j] + bs[c16 + 8 + j];
            xt1[j] = f2bf(v2); xn1[j] = f2bf(n2);
        }
        *(bf16x8*)&Xt16[o]     = xt0;
        *(bf16x8*)&Xn16[o]     = xn0;
        *(bf16x8*)&Xt16[o + 8] = xt1;
        *(bf16x8*)&Xn16[o + 8] = xn1;
    }
}

// ---------------------------------------------------------------------------
// Kernel 2: fused Q/K/V projections. Grid 1024 (16 rows/block, 4 blocks/CU).
// wave0: Q (+mask*w_qm, cosine norm); wave1: K (cosine norm);
// waves 2,3: V half-columns each -> transposed store to V16t [B,C,N].
// All A/B fragments direct from global (L1/L2-resident).
// ---------------------------------------------------------------------------
__global__ __launch_bounds__(256) void proj_kernel(
    const short* __restrict__ Xn16, const short* __restrict__ Xt16,
    const short* __restrict__ W16, const float* __restrict__ mask,
    const float* __restrict__ w_qm,
    short* __restrict__ Q16, short* __restrict__ K16, short* __restrict__ V16t)
{
    __shared__ short Vt[256 * 24];
    const int tid = threadIdx.x;
    const int w = tid >> 6, lane = tid & 63, ln = lane & 15, quad = lane >> 4;
    const int m0 = blockIdx.x * 16;

    if (w < 2) {
        const int woff = (w == 0) ? OFF_WQ : OFF_WK;
        f32x4 acc[6];
        #pragma unroll
        for (int i = 0; i < 6; ++i) acc[i] = (f32x4){0.f, 0.f, 0.f, 0.f};
        #pragma unroll
        for (int kt = 0; kt < 8; ++kt) {
            bf16x8 af = *(const bf16x8*)&Xn16[(size_t)(m0 + ln) * 256 + kt * 32 + quad * 8];
            #pragma unroll
            for (int nt = 0; nt < 6; ++nt) {
                bf16x8 bf = *(const bf16x8*)&W16[woff + (size_t)(nt * 16 + ln) * 256 + kt * 32 + quad * 8];
                acc[nt] = __builtin_amdgcn_mfma_f32_16x16x32_bf16(af, bf, acc[nt], 0, 0, 0);
            }
        }
        short* outp = (w == 0) ? Q16 : K16;
        #pragma unroll
        for (int r = 0; r < 4; ++r) {
            int row = m0 + quad * 4 + r;
            float mrow = (w == 0) ? mask[row] : 0.f;
            float vals[6];
            float ss = 0.f;
            #pragma unroll
            for (int nt = 0; nt < 6; ++nt) {
                float v = acc[nt][r];
                if (w == 0) v += mrow * w_qm[nt * 16 + ln];
                vals[nt] = v;
                ss += v * v;
            }
            ss += __shfl_xor(ss, 1, 64); ss += __shfl_xor(ss, 2, 64);
            ss += __shfl_xor(ss, 4, 64); ss += __shfl_xor(ss, 8, 64);
            float sc = 1.0f / fmaxf(sqrtf(ss), 1e-12f);
            #pragma unroll
            for (int nt = 0; nt < 6; ++nt)
                outp[(size_t)row * EE + nt * 16 + ln] = f2bf(vals[nt] * sc);
        }
    } else {
        const int wn = w - 2;
        f32x4 acc[8];
        #pragma unroll
        for (int i = 0; i < 8; ++i) acc[i] = (f32x4){0.f, 0.f, 0.f, 0.f};
        #pragma unroll
        for (int kt = 0; kt < 8; ++kt) {
            bf16x8 af = *(const bf16x8*)&Xt16[(size_t)(m0 + ln) * 256 + kt * 32 + quad * 8];
            #pragma unroll
            for (int nt = 0; nt < 8; ++nt) {
                int col = wn * 128 + nt * 16 + ln;
                bf16x8 bf = *(const bf16x8*)&W16[OFF_WV + (size_t)col * 256 + kt * 32 + quad * 8];
                acc[nt] = __builtin_amdgcn_mfma_f32_16x16x32_bf16(af, bf, acc[nt], 0, 0, 0);
            }
        }
        #pragma unroll
        for (int nt = 0; nt < 8; ++nt) {
            int ch = wn * 128 + nt * 16 + ln;
            #pragma unroll
            for (int r = 0; r < 4; ++r)
                Vt[ch * 24 + quad * 4 + r] = f2bf(acc[nt][r]);
        }
    }
    __syncthreads();
    const int b = m0 >> 12, p0l = m0 & 4095;
    #pragma unroll
    for (int j = 0; j < 2; ++j) {
        int idx = tid + j * 256;
        int ch = idx >> 1, p8 = (idx & 1) * 8;
        *(bf16x8*)&V16t[((size_t)b * CC + ch) * NN + p0l + p8] =
            *(const bf16x8*)&Vt[ch * 24 + p8];
    }
}

// ---------------------------------------------------------------------------
// Kernel 3: LDS-staged MFMA attention, 4-way K-split, 4 blocks/CU.
// Grid 1024 = 4 key-groups x 256 q-tiles. 4 waves share K/V LDS tiles.
// Changes vs R6: flg -> direct mask loads; P stores paired into conflict-free
// ds_write_b32 (even lanes, neighbor via shfl_xor).
// ---------------------------------------------------------------------------
__global__ __launch_bounds__(256, 4) void attn_kernel(
    const short* __restrict__ Q16, const short* __restrict__ K16,
    const short* __restrict__ V16t, const float* __restrict__ mask,
    short* __restrict__ Opart, float* __restrict__ Lpart)
{
    __shared__ short Vs[8192];        // [j 0..3][ch 0..255] chunks of 8 shorts
    __shared__ short Ks[3072];        // [p 0..11][key 0..31] chunks of 8 shorts
    __shared__ short Ps[64 * 40];

    const int tid = threadIdx.x;
    const int w = tid >> 6, lane = tid & 63, ln = lane & 15, quad = lane >> 4;
    const int bidx = blockIdx.x;
    const int kg = bidx >> 8;                       // 0..3 key group
    const int qg = bidx & 255;
    const int b  = (qg & 7) >> 1;                   // XCD-pinned batch
    const int qt = ((qg >> 3) << 1) | (qg & 1);     // 0..63
    const int q0 = qt * 64;
    const size_t bN = (size_t)b * NN;
    const size_t bCC = (size_t)b * CC;
    const int kbase = kg * 1024;
    const float C1 = 1.02062072615966f;             // 10/sqrt(96)
    const int wbase = w * 64;

    bf16x8 qf[3];
    #pragma unroll
    for (int e = 0; e < 3; ++e)
        qf[e] = *(const bf16x8*)&Q16[(bN + q0 + w * 16 + ln) * EE + e * 32 + quad * 8];

    f32x4 acc[4][4];
    #pragma unroll
    for (int mt = 0; mt < 4; ++mt)
        #pragma unroll
        for (int nt = 0; nt < 4; ++nt) acc[mt][nt] = (f32x4){0.f, 0.f, 0.f, 0.f};
    float lsum[4] = {0.f, 0.f, 0.f, 0.f};

    // prologue: K(0)
    gld16(&Ks[wbase * 8], &K16[(bN + kbase + (tid & 31)) * EE + (tid >> 5) * 8]);
    if (w < 2)
        gld16(&Ks[(256 + wbase) * 8],
              &K16[(bN + kbase + (tid & 31)) * EE + (8 + (tid >> 5)) * 8]);
    __syncthreads();

    for (int it = 0; it < 32; ++it) {
        const int k0 = kbase + it * 32;
        // V(it) DMA into the single buffer (PV of it-1 finished at barrier2)
        #pragma unroll
        for (int i = 0; i < 4; ++i)
            gld16(&Vs[(i * 256 + wbase) * 8], &V16t[(bCC + tid) * NN + k0 + i * 8]);

        float mk0 = mask[bN + k0 + ln];
        float mk1 = mask[bN + k0 + 16 + ln];

        // ---- S = Q K^T (K from LDS) ----
        f32x4 s0 = (f32x4){0.f,0.f,0.f,0.f}, s1 = s0;
        #pragma unroll
        for (int e = 0; e < 3; ++e) {
            bf16x8 kf0 = *(const bf16x8*)&Ks[((e * 4 + quad) * 32 + ln) * 8];
            bf16x8 kf1 = *(const bf16x8*)&Ks[((e * 4 + quad) * 32 + 16 + ln) * 8];
            s0 = __builtin_amdgcn_mfma_f32_16x16x32_bf16(qf[e], kf0, s0, 0, 0, 0);
            s1 = __builtin_amdgcn_mfma_f32_16x16x32_bf16(qf[e], kf1, s1, 0, 0, 0);
        }
        bool z0 = mk0 >= 0.5f;
        bool z1 = mk1 >= 0.5f;
        #pragma unroll
        for (int r = 0; r < 4; ++r) {
            float p0 = z0 ? 0.f : __expf(fmaf(s0[r], C1, -C1));
            float p1 = z1 ? 0.f : __expf(fmaf(s1[r], C1, -C1));
            lsum[r] += p0 + p1;
            unsigned a0 = (unsigned short)f2bf(p0);
            unsigned a1 = (unsigned short)f2bf(p1);
            unsigned b0 = (unsigned)__shfl_xor((int)a0, 1, 64);
            unsigned b1 = (unsigned)__shfl_xor((int)a1, 1, 64);
            if (!(ln & 1)) {
                int row = w * 16 + quad * 4 + r;
                *(unsigned*)&Ps[row * 40 + ln]      = a0 | (b0 << 16);
                *(unsigned*)&Ps[row * 40 + 16 + ln] = a1 | (b1 << 16);
            }
        }
        __syncthreads();        // barrier1: drains V(it); Ps visible; Ks free

        // K(it+1) prefetch (drained by barrier2)
        if (it + 1 < 32) {
            const int k0n = k0 + 32;
            gld16(&Ks[wbase * 8], &K16[(bN + k0n + (tid & 31)) * EE + (tid >> 5) * 8]);
            if (w < 2)
                gld16(&Ks[(256 + wbase) * 8],
                      &K16[(bN + k0n + (tid & 31)) * EE + (8 + (tid >> 5)) * 8]);
        }

        // ---- PV: all 64 q x this wave's 64 channels ----
        bf16x8 pf[4], vf[4];
        #pragma unroll
        for (int mt = 0; mt < 4; ++mt)
            pf[mt] = *(const bf16x8*)&Ps[(mt * 16 + ln) * 40 + quad * 8];
        #pragma unroll
        for (int nt = 0; nt < 4; ++nt)
            vf[nt] = *(const bf16x8*)&Vs[(quad * 256 + wbase + nt * 16 + ln) * 8];
        #pragma unroll
        for (int mt = 0; mt < 4; ++mt)
            #pragma unroll
            for (int nt = 0; nt < 4; ++nt)
                acc[mt][nt] = __builtin_amdgcn_mfma_f32_16x16x32_bf16(pf[mt], vf[nt], acc[mt][nt], 0, 0, 0);
        __syncthreads();        // barrier2: drains K(it+1); frees Ps/Vs
    }

    // ---- epilogue: partial l and partial O ----
    #pragma unroll
    for (int r = 0; r < 4; ++r) {
        float l = lsum[r];
        l += __shfl_xor(l, 1, 64); l += __shfl_xor(l, 2, 64);
        l += __shfl_xor(l, 4, 64); l += __shfl_xor(l, 8, 64);
        if (ln == 0)
            Lpart[(size_t)kg * NTOT + bN + q0 + w * 16 + quad * 4 + r] = l;
    }
    #pragma unroll
    for (int mt = 0; mt < 4; ++mt)
        #pragma unroll
        for (int nt = 0; nt < 4; ++nt)
            #pragma unroll
            for (int r = 0; r < 4; ++r)
                Opart[((size_t)kg * NTOT + bN + q0 + mt * 16 + quad * 4 + r) * 256
                      + wbase + nt * 16 + ln] = f2bf(acc[mt][nt][r]);
}

// ---------------------------------------------------------------------------
// Kernel 4: mega-fused epilogue, 16 rows/block, grid 1024 (4 blocks/CU).
// P1: O=(sum 4 Opart)/l -> Olds; Xnm -> Dlds upper.  P2: D1=O@wo^T - Xt.
// P3: Hid=gelu([D1|Xnm]@wd1^T) -> Hlds.  P4: Cor=Hid@wd2^T -> Clds.
// P5: gate GEMM + delta -> tileB; store out = x + delta (transposed).
// ---------------------------------------------------------------------------
__global__ __launch_bounds__(256, 4) void epi_kernel(
    const short* __restrict__ Opart, const float* __restrict__ Lpart,
    const short* __restrict__ W16, const short* __restrict__ Xt16,
    const short* __restrict__ Xn16, const float* __restrict__ mask,
    const float* __restrict__ rs, const float* __restrict__ x,
    float* __restrict__ out)
{
    __shared__ char lds[27264];
    short* Olds  = (short*)lds;              // 16 x 264 (P1-P2); Hlds after
    short* Hlds  = (short*)lds;
    short* Dlds  = (short*)(lds + 8448);     // 16 x 528 [D1 | Xnm] (P1-P3)
    short* Clds  = (short*)(lds + 8448);     // 16 x 264 (P4+, Dlds rows0-7 dead)
    short* tileB = (short*)(lds + 16896);    // 256 x 20 (P5, Dlds rows8-15 dead)
    float* lsh   = (float*)(lds + 27136);    // 16 floats

    const int tid = threadIdx.x;
    const int w = tid >> 6, lane = tid & 63, ln = lane & 15, quad = lane >> 4;
    const int m0 = blockIdx.x * 16;
    const int b = m0 >> 12, p0l = m0 & 4095;

    if (tid < 16) {
        int g = m0 + tid;
        lsh[tid] = 1.0f / (Lpart[g] + Lpart[NTOT + g] + Lpart[2 * NTOT + g] + Lpart[3 * NTOT + g]);
    }
    __syncthreads();

    // ---- P1: reduce Opart, normalize -> Olds; Xnm -> Dlds upper ----
    #pragma unroll
    for (int j = 0; j < 2; ++j) {
        int idx = tid + j * 256;
        int q = idx >> 5, ch8 = (idx & 31) * 8;
        size_t base = (size_t)(m0 + q) * 256 + ch8;
        bf16x8 a0 = *(const bf16x8*)&Opart[base];
        bf16x8 a1 = *(const bf16x8*)&Opart[(size_t)NTOT * 256 + base];
        bf16x8 a2 = *(const bf16x8*)&Opart[(size_t)2 * NTOT * 256 + base];
        bf16x8 a3 = *(const bf16x8*)&Opart[(size_t)3 * NTOT * 256 + base];
        float linv = lsh[q];
        bf16x8 o;
        #pragma unroll
        for (int e = 0; e < 8; ++e)
            o[e] = f2bf((bf2f(a0[e]) + bf2f(a1[e]) + bf2f(a2[e]) + bf2f(a3[e])) * linv);
        *(bf16x8*)&Olds[q * 264 + ch8] = o;
        bf16x8 xn = *(const bf16x8*)&Xn16[base];
        float mq = mask[m0 + q];
        bf16x8 xm;
        #pragma unroll
        for (int e = 0; e < 8; ++e) xm[e] = f2bf(bf2f(xn[e]) * mq);
        *(bf16x8*)&Dlds[q * 528 + 256 + ch8] = xm;
    }
    __syncthreads();

    // ---- P2: D1 = O@wo^T - Xt -> Dlds lower ----
    {
        f32x4 acc[4];
        #pragma unroll
        for (int i = 0; i < 4; ++i) acc[i] = (f32x4){0.f, 0.f, 0.f, 0.f};
        #pragma unroll
        for (int kt = 0; kt < 8; ++kt) {
            bf16x8 af = *(const bf16x8*)&Olds[ln * 264 + kt * 32 + quad * 8];
            #pragma unroll
            for (int nt = 0; nt < 4; ++nt) {
                int col = w * 64 + nt * 16 + ln;
                bf16x8 bf = *(const bf16x8*)&W16[OFF_WO + (size_t)col * 256 + kt * 32 + quad * 8];
                acc[nt] = __builtin_amdgcn_mfma_f32_16x16x32_bf16(af, bf, acc[nt], 0, 0, 0);
            }
        }
        #pragma unroll
        for (int nt = 0; nt < 4; ++nt) {
            int col = w * 64 + nt * 16 + ln;
            #pragma unroll
            for (int r = 0; r < 4; ++r) {
                int row = quad * 4 + r;
                float v = acc[nt][r] - bf2f(Xt16[(size_t)(m0 + row) * 256 + col]);
                Dlds[row * 528 + col] = f2bf(v);
            }
        }
    }
    __syncthreads();

    // ---- P3: Hid = gelu([D1|Xnm] @ wd1^T) -> Hlds ----
    {
        f32x4 acc[4];
        #pragma unroll
        for (int i = 0; i < 4; ++i) acc[i] = (f32x4){0.f, 0.f, 0.f, 0.f};
        #pragma unroll
        for (int kt = 0; kt < 16; ++kt) {
            bf16x8 af = *(const bf16x8*)&Dlds[ln * 528 + kt * 32 + quad * 8];
            #pragma unroll
            for (int nt = 0; nt < 4; ++nt) {
                int col = w * 64 + nt * 16 + ln;
                bf16x8 bf = *(const bf16x8*)&W16[OFF_WD1 + (size_t)col * 512 + kt * 32 + quad * 8];
                acc[nt] = __builtin_amdgcn_mfma_f32_16x16x32_bf16(af, bf, acc[nt], 0, 0, 0);
            }
        }
        #pragma unroll
        for (int nt = 0; nt < 4; ++nt) {
            int col = w * 64 + nt * 16 + ln;
            #pragma unroll
            for (int r = 0; r < 4; ++r)
                Hlds[(quad * 4 + r) * 264 + col] = f2bf(gelu_exact(acc[nt][r]));
        }
    }
    __syncthreads();

    // ---- P4: Cor = Hid @ wd2^T -> Clds ----
    {
        f32x4 acc[4];
        #pragma unroll
        for (int i = 0; i < 4; ++i) acc[i] = (f32x4){0.f, 0.f, 0.f, 0.f};
        #pragma unroll
        for (int kt = 0; kt < 8; ++kt) {
            bf16x8 af = *(const bf16x8*)&Hlds[ln * 264 + kt * 32 + quad * 8];
            #pragma unroll
            for (int nt = 0; nt < 4; ++nt) {
                int col = w * 64 + nt * 16 + ln;
                bf16x8 bf = *(const bf16x8*)&W16[OFF_WD2 + (size_t)col * 256 + kt * 32 + quad * 8];
                acc[nt] = __builtin_amdgcn_mfma_f32_16x16x32_bf16(af, bf, acc[nt], 0, 0, 0);
            }
        }
        #pragma unroll
        for (int nt = 0; nt < 4; ++nt) {
            int col = w * 64 + nt * 16 + ln;
            #pragma unroll
            for (int r = 0; r < 4; ++r)
                Clds[(quad * 4 + r) * 264 + col] = f2bf(acc[nt][r]);
        }
    }
    __syncthreads();

    // ---- P5: gate GEMM + delta -> tileB ----
    {
        f32x4 acc[4];
        #pragma unroll
        for (int i = 0; i < 4; ++i) acc[i] = (f32x4){0.f, 0.f, 0.f, 0.f};
        #pragma unroll
        for (int kt = 0; kt < 8; ++kt) {
            bf16x8 af = *(const bf16x8*)&Clds[ln * 264 + kt * 32 + quad * 8];
            #pragma unroll
            for (int nt = 0; nt < 4; ++nt) {
                int col = w * 64 + nt * 16 + ln;
                bf16x8 bf = *(const bf16x8*)&W16[OFF_WG + (size_t)col * 256 + kt * 32 + quad * 8];
                acc[nt] = __builtin_amdgcn_mfma_f32_16x16x32_bf16(af, bf, acc[nt], 0, 0, 0);
            }
        }
        float trs = tanhf(rs[0]);
        #pragma unroll
        for (int nt = 0; nt < 4; ++nt) {
            int col = w * 64 + nt * 16 + ln;
            float wgl = bf2f(W16[OFF_WGL + col]);
            #pragma unroll
            for (int r = 0; r < 4; ++r) {
                int row = quad * 4 + r;
                float mrow = mask[m0 + row];
                float logit = acc[nt][r] + mrow * wgl;
                float gate = mrow / (1.0f + __expf(-logit));
                float corr = bf2f(Clds[row * 264 + col]);
                tileB[col * 20 + row] = f2bf(trs * gate * corr);
            }
        }
    }
    __syncthreads();

    // ---- store: out[b,ch,p] = x + delta (thread = one channel) ----
    {
        int ch = tid;
        size_t o = ((size_t)b * CC + ch) * NN + p0l;
        #pragma unroll
        for (int i = 0; i < 4; ++i) {
            bf16x4 d = *(const bf16x4*)&tileB[ch * 20 + i * 4];
            float4 xv = *(const float4*)&x[o + i * 4];
            float4 ov;
            ov.x = xv.x + bf2f(d[0]); ov.y = xv.y + bf2f(d[1]);
            ov.z = xv.z + bf2f(d[2]); ov.w = xv.w + bf2f(d[3]);
            *(float4*)&out[o + i * 4] = ov;
        }
    }
}

// ---------------------------------------------------------------------------
extern "C" void kernel_launch(void* const* d_in, const int* in_sizes, int n_in,
                              void* d_out, int out_size, void* d_ws, size_t ws_size,
                              hipStream_t stream) {
    const float* x     = (const float*)d_in[0];
    const float* mask  = (const float*)d_in[1];
    const float* gamma = (const float*)d_in[2];
    const float* beta  = (const float*)d_in[3];
    const float* wq    = (const float*)d_in[4];
    const float* wk    = (const float*)d_in[5];
    const float* wv    = (const float*)d_in[6];
    const float* w_out = (const float*)d_in[7];
    const float* w_qm  = (const float*)d_in[8];
    const float* wd1   = (const float*)d_in[9];
    const float* wd2   = (const float*)d_in[10];
    const float* wg    = (const float*)d_in[11];
    const float* rs    = (const float*)d_in[12];
    float* out = (float*)d_out;

    const size_t NC = (size_t)NTOT * CC;
    const size_t NE = (size_t)NTOT * EE;
    short* Xn16  = (short*)d_ws;        // NC
    short* Xt16  = Xn16 + NC;           // NC
    short* Q16   = Xt16 + NC;           // NE
    short* K16   = Q16 + NE;            // NE
    short* V16t  = K16 + NE;            // NC
    short* W16   = V16t + NC;           // W16_TOTAL
    short* Opart = W16 + W16_TOTAL;     // 4*NC
    float* Lpart = (float*)(Opart + 4 * NC);   // 4*NTOT f32
    // ~66 MB total

    ln_kernel<<<1024, 256, 0, stream>>>(x, gamma, beta, wq, wk, wv, w_out,
                                        wd1, wd2, wg, W16, Xt16, Xn16);
    proj_kernel<<<1024, 256, 0, stream>>>(Xn16, Xt16, W16, mask, w_qm,
                                          Q16, K16, V16t);
    attn_kernel<<<1024, 256, 0, stream>>>(Q16, K16, V16t, mask, Opart, Lpart);
    epi_kernel<<<1024, 256, 0, stream>>>(Opart, Lpart, W16, Xt16, Xn16, mask,
                                         rs, x, out);
}